// Round 1
// baseline (547.361 us; speedup 1.0000x reference)
//
#include <hip/hip_runtime.h>
#include <hip/hip_bf16.h>

// Problem constants
#define BB 4096
#define DD 512
#define HH 512
#define CC 8
#define N3H 1536
#define N4H 2048
#define NEG_BIG -1000000.0f

// ---------------------------------------------------------------------------
// K0: per-(b,c) all-zero row detection. One wave (64 lanes) per row of 512.
// maskmul[row] = 1.0 if any nonzero, else -1e6.
// ---------------------------------------------------------------------------
__global__ __launch_bounds__(256) void k_mask(const float* __restrict__ c_in,
                                              float* __restrict__ maskmul) {
    const int wid  = threadIdx.x >> 6;
    const int lane = threadIdx.x & 63;
    const int row  = blockIdx.x * 4 + wid;   // 0..32767
    const float* p = c_in + (size_t)row * HH + lane * 4;
    bool nz = false;
#pragma unroll
    for (int it = 0; it < 2; ++it) {
        const float4 v = *(const float4*)(p + it * 256);
        nz |= (v.x != 0.f) | (v.y != 0.f) | (v.z != 0.f) | (v.w != 0.f);
    }
    const unsigned long long m = __ballot(nz);
    if (lane == 0) maskmul[row] = (m != 0ULL) ? 1.0f : NEG_BIG;
}

// ---------------------------------------------------------------------------
// fp32 tiled GEMM accumulate helper: 128x128 block tile, BK=16, 256 threads,
// 8x8 microtile per thread. A row-major (M x K, lda), B row-major (K x N, ldb)
// with column offset bcol. Accumulates into acc.
// ---------------------------------------------------------------------------
__device__ __forceinline__ void gemm_accum_f32(
    const float* __restrict__ A, int lda,
    const float* __restrict__ Bm, int ldb, int bcol,
    int K, int m0, int tid,
    float (&As)[16][132], float (&Bs)[16][132],
    float (&acc)[8][8]) {
    const int tx = tid & 15, ty = tid >> 4;
    for (int k0 = 0; k0 < K; k0 += 16) {
        __syncthreads();
        // ---- stage A tile (128 rows x 16 k), transposed into As[k][m]
        {
            const int r  = tid >> 2;
            const int kg = (tid & 3) * 4;
#pragma unroll
            for (int it = 0; it < 2; ++it) {
                const int rr = r + it * 64;
                const float4 v = *(const float4*)&A[(size_t)(m0 + rr) * lda + k0 + kg];
                As[kg + 0][rr] = v.x;
                As[kg + 1][rr] = v.y;
                As[kg + 2][rr] = v.z;
                As[kg + 3][rr] = v.w;
            }
        }
        // ---- stage B tile (16 k x 128 cols) into Bs[k][n]
        {
            const int kr = tid >> 5;         // 0..7
            const int c  = (tid & 31) * 4;   // 0..124
#pragma unroll
            for (int it = 0; it < 2; ++it) {
                const float4 v = *(const float4*)&Bm[(size_t)(k0 + kr + it * 8) * ldb + bcol + c];
                *(float4*)&Bs[kr + it * 8][c] = v;
            }
        }
        __syncthreads();
        // ---- 8x8 outer-product microkernel
#pragma unroll
        for (int k = 0; k < 16; ++k) {
            const float4 a0 = *(const float4*)&As[k][ty * 4];
            const float4 a1 = *(const float4*)&As[k][64 + ty * 4];
            const float4 b0 = *(const float4*)&Bs[k][tx * 4];
            const float4 b1 = *(const float4*)&Bs[k][64 + tx * 4];
            const float a[8] = {a0.x, a0.y, a0.z, a0.w, a1.x, a1.y, a1.z, a1.w};
            const float b[8] = {b0.x, b0.y, b0.z, b0.w, b1.x, b1.y, b1.z, b1.w};
#pragma unroll
            for (int i = 0; i < 8; ++i)
#pragma unroll
                for (int j = 0; j < 8; ++j)
                    acc[i][j] = fmaf(a[i], b[j], acc[i][j]);
        }
    }
}

// ---------------------------------------------------------------------------
// K1: gates4 (B x 2048).
//   cols [0,1536):  input@W_ih + h0@W_hh + bias; act: sigmoid/sigmoid/tanh
//   cols [1536,2048): input@alphaW_ih + alpha_bias; no activation
// ---------------------------------------------------------------------------
__global__ __launch_bounds__(256, 2) void k_gates(
    const float* __restrict__ input, const float* __restrict__ h0,
    const float* __restrict__ Wih, const float* __restrict__ Whh,
    const float* __restrict__ bias, const float* __restrict__ aWih,
    const float* __restrict__ abias, float* __restrict__ gates4) {
    __shared__ float As[16][132];
    __shared__ float Bs[16][132];
    float acc[8][8];
#pragma unroll
    for (int i = 0; i < 8; ++i)
#pragma unroll
        for (int j = 0; j < 8; ++j) acc[i][j] = 0.f;

    const int n0 = blockIdx.x * 128;
    const int m0 = blockIdx.y * 128;
    const int tid = threadIdx.x;
    const int tx = tid & 15, ty = tid >> 4;

    const bool isGate = (n0 < N3H);
    if (isGate) {
        gemm_accum_f32(input, DD, Wih, N3H, n0, DD, m0, tid, As, Bs, acc);
        gemm_accum_f32(h0, HH, Whh, N3H, n0, HH, m0, tid, As, Bs, acc);
    } else {
        gemm_accum_f32(input, DD, aWih, HH, n0 - N3H, DD, m0, tid, As, Bs, acc);
    }

    const float* bvec = isGate ? (bias + n0) : (abias + (n0 - N3H));
    const int act = isGate ? (n0 >> 9) : 3;  // 0,1: sigmoid; 2: tanh; 3: none

#pragma unroll
    for (int i = 0; i < 8; ++i) {
        const int row = m0 + ((i < 4) ? (ty * 4 + i) : (64 + ty * 4 + i - 4));
#pragma unroll
        for (int jg = 0; jg < 2; ++jg) {
            const int colq = jg * 64 + tx * 4;
            float4 v;
            float* vp = &v.x;
#pragma unroll
            for (int jj = 0; jj < 4; ++jj) {
                float x = acc[i][jg * 4 + jj] + bvec[colq + jj];
                if (act <= 1)      x = 1.f / (1.f + expf(-x));
                else if (act == 2) x = tanhf(x);
                vp[jj] = x;
            }
            *(float4*)&gates4[(size_t)row * N4H + n0 + colq] = v;
        }
    }
}

// ---------------------------------------------------------------------------
// K2: alpha_ws (32768 x 512) = exp(sigmoid(c_flat@aWhh + alpha_wi) * mask)
// ---------------------------------------------------------------------------
__global__ __launch_bounds__(256, 2) void k_alpha(
    const float* __restrict__ c_in, const float* __restrict__ aWhh,
    const float* __restrict__ gates4, const float* __restrict__ maskmul,
    float* __restrict__ alpha_ws) {
    __shared__ float As[16][132];
    __shared__ float Bs[16][132];
    float acc[8][8];
#pragma unroll
    for (int i = 0; i < 8; ++i)
#pragma unroll
        for (int j = 0; j < 8; ++j) acc[i][j] = 0.f;

    const int n0 = blockIdx.x * 128;
    const int m0 = blockIdx.y * 128;
    const int tid = threadIdx.x;
    const int tx = tid & 15, ty = tid >> 4;

    gemm_accum_f32(c_in, HH, aWhh, HH, n0, HH, m0, tid, As, Bs, acc);

#pragma unroll
    for (int i = 0; i < 8; ++i) {
        const int r = m0 + ((i < 4) ? (ty * 4 + i) : (64 + ty * 4 + i - 4));
        const int b = r >> 3;
        const float mult = maskmul[r];
        const float* awrow = gates4 + (size_t)b * N4H + N3H;
#pragma unroll
        for (int jg = 0; jg < 2; ++jg) {
            const int colq = jg * 64 + tx * 4;
            const int h = n0 + colq;
            float4 v;
            float* vp = &v.x;
#pragma unroll
            for (int jj = 0; jj < 4; ++jj) {
                const float x = acc[i][jg * 4 + jj] + awrow[h + jj];
                const float s = 1.f / (1.f + expf(-x));
                vp[jj] = expf(s * mult);  // masked rows -> exp(-huge) == 0
            }
            *(float4*)&alpha_ws[(size_t)r * HH + h] = v;
        }
    }
}

// ---------------------------------------------------------------------------
// K3: final merge. Per (b, 4 h's): exp-normalize over {i} u {8 cells},
// c1 = weighted sum, h1 = o * tanh(c1).
// ---------------------------------------------------------------------------
__global__ __launch_bounds__(256) void k_final(
    const float* __restrict__ gates4, const float* __restrict__ alpha_ws,
    const float* __restrict__ c_in, float* __restrict__ out) {
    const int idx = blockIdx.x * 256 + threadIdx.x;  // 0..524287
    const int b = idx >> 7;
    const int h = (idx & 127) << 2;

    const float4 iv = *(const float4*)&gates4[(size_t)b * N4H + h];
    const float4 ov = *(const float4*)&gates4[(size_t)b * N4H + 512 + h];
    const float4 gv = *(const float4*)&gates4[(size_t)b * N4H + 1024 + h];

    float num[4], den[4];
    {
        const float* ip = &iv.x;
        const float* gp = &gv.x;
#pragma unroll
        for (int jj = 0; jj < 4; ++jj) {
            const float e = expf(ip[jj]);   // i already sigmoid'ed in K1
            num[jj] = gp[jj] * e;           // g already tanh'ed in K1
            den[jj] = e;
        }
    }
    const size_t base = (size_t)b * (CC * HH) + h;
#pragma unroll
    for (int c = 0; c < CC; ++c) {
        const float4 a = *(const float4*)&alpha_ws[base + c * HH];
        const float4 v = *(const float4*)&c_in[base + c * HH];
        num[0] = fmaf(v.x, a.x, num[0]); den[0] += a.x;
        num[1] = fmaf(v.y, a.y, num[1]); den[1] += a.y;
        num[2] = fmaf(v.z, a.z, num[2]); den[2] += a.z;
        num[3] = fmaf(v.w, a.w, num[3]); den[3] += a.w;
    }
    float4 h1, c1;
    float* hp = &h1.x;
    float* cp = &c1.x;
    const float* op = &ov.x;
#pragma unroll
    for (int jj = 0; jj < 4; ++jj) {
        const float c1v = num[jj] / den[jj];
        cp[jj] = c1v;
        hp[jj] = op[jj] * tanhf(c1v);
    }
    *(float4*)&out[(size_t)b * HH + h] = h1;
    *(float4*)&out[(size_t)BB * HH + (size_t)b * HH + h] = c1;
}

// ---------------------------------------------------------------------------
extern "C" void kernel_launch(void* const* d_in, const int* in_sizes, int n_in,
                              void* d_out, int out_size, void* d_ws, size_t ws_size,
                              hipStream_t stream) {
    const float* input = (const float*)d_in[0];
    const float* h0    = (const float*)d_in[1];
    // d_in[2] = c_0 (unused by reference)
    const float* c_in  = (const float*)d_in[3];
    const float* Wih   = (const float*)d_in[4];
    const float* Whh   = (const float*)d_in[5];
    const float* bias  = (const float*)d_in[6];
    const float* aWih  = (const float*)d_in[7];
    const float* aWhh  = (const float*)d_in[8];
    const float* abias = (const float*)d_in[9];
    float* out = (float*)d_out;

    // workspace layout: gates4 (B x 2048), alpha_ws (B*C x H), maskmul (B*C)
    float* gates4   = (float*)d_ws;
    float* alpha_ws = gates4 + (size_t)BB * N4H;           // +32 MB
    float* maskmul  = alpha_ws + (size_t)BB * CC * HH;     // +64 MB

    k_mask<<<dim3(BB * CC / 4), dim3(256), 0, stream>>>(c_in, maskmul);
    k_gates<<<dim3(N4H / 128, BB / 128), dim3(256), 0, stream>>>(
        input, h0, Wih, Whh, bias, aWih, abias, gates4);
    k_alpha<<<dim3(HH / 128, BB * CC / 128), dim3(256), 0, stream>>>(
        c_in, aWhh, gates4, maskmul, alpha_ws);
    k_final<<<dim3(BB * HH / 4 / 256), dim3(256), 0, stream>>>(
        gates4, alpha_ws, c_in, out);
}

// Round 2
// 214.879 us; speedup vs baseline: 2.5473x; 2.5473x over previous
//
#include <hip/hip_runtime.h>
#include <hip/hip_bf16.h>

// Problem constants
#define BB 4096
#define DD 512
#define HH 512
#define CC 8
#define N3H 1536
#define N4H 2048
#define NEG_BIG -1000000.0f

typedef __bf16 bf16x8 __attribute__((ext_vector_type(8)));
typedef float  f32x4  __attribute__((ext_vector_type(4)));

#define GL_LDS(gp, lp) \
    __builtin_amdgcn_global_load_lds( \
        (const __attribute__((address_space(1))) void*)(gp), \
        (__attribute__((address_space(3))) void*)(lp), 16, 0, 0)

// ---------------------------------------------------------------------------
// P0: convert c_input (32768 x 512) fp32 -> bf16, one wave per row, and fold
// the all-zero-row mask detection into the same pass (64B/lane read).
// ---------------------------------------------------------------------------
__global__ __launch_bounds__(256) void k_prep_c(const float* __restrict__ c_in,
                                                __bf16* __restrict__ c_bf,
                                                float* __restrict__ maskmul) {
    const int wid  = threadIdx.x >> 6;
    const int lane = threadIdx.x & 63;
    const int row  = blockIdx.x * 4 + wid;   // 0..32767
    const float* p = c_in + (size_t)row * HH + lane * 8;
    const float4 v0 = *(const float4*)p;
    const float4 v1 = *(const float4*)(p + 4);
    bf16x8 o;
    o[0] = (__bf16)v0.x; o[1] = (__bf16)v0.y; o[2] = (__bf16)v0.z; o[3] = (__bf16)v0.w;
    o[4] = (__bf16)v1.x; o[5] = (__bf16)v1.y; o[6] = (__bf16)v1.z; o[7] = (__bf16)v1.w;
    *(bf16x8*)&c_bf[(size_t)row * HH + lane * 8] = o;
    const bool nz = (v0.x != 0.f) | (v0.y != 0.f) | (v0.z != 0.f) | (v0.w != 0.f) |
                    (v1.x != 0.f) | (v1.y != 0.f) | (v1.z != 0.f) | (v1.w != 0.f);
    const unsigned long long m = __ballot(nz);
    if (lane == 0) maskmul[row] = (m != 0ULL) ? 1.0f : NEG_BIG;
}

// ---------------------------------------------------------------------------
// P1: convert input (4096x512) and h0 (4096x512) to bf16, 8 elems/thread.
// ---------------------------------------------------------------------------
__global__ __launch_bounds__(256) void k_prep_ih(const float* __restrict__ input,
                                                 const float* __restrict__ h0,
                                                 __bf16* __restrict__ in_bf,
                                                 __bf16* __restrict__ h0_bf) {
    const size_t NIN = (size_t)BB * DD;
    size_t i = ((size_t)blockIdx.x * 256 + threadIdx.x) * 8;
    const float* src;
    __bf16* dst;
    if (i < NIN) { src = input + i; dst = in_bf + i; }
    else         { src = h0 + (i - NIN); dst = h0_bf + (i - NIN); }
    const float4 v0 = *(const float4*)src;
    const float4 v1 = *(const float4*)(src + 4);
    bf16x8 o;
    o[0] = (__bf16)v0.x; o[1] = (__bf16)v0.y; o[2] = (__bf16)v0.z; o[3] = (__bf16)v0.w;
    o[4] = (__bf16)v1.x; o[5] = (__bf16)v1.y; o[6] = (__bf16)v1.z; o[7] = (__bf16)v1.w;
    *(bf16x8*)dst = o;
}

// ---------------------------------------------------------------------------
// P2: transpose+convert all 4 weights into bf16 B^T (N x K, K=512) layout.
// 64x64 LDS tile transpose, 512 total tiles across the 4 weights.
// ---------------------------------------------------------------------------
__global__ __launch_bounds__(256) void k_prep_w(
    const float* __restrict__ Wih, const float* __restrict__ Whh,
    const float* __restrict__ aWih, const float* __restrict__ aWhh,
    __bf16* __restrict__ WihT, __bf16* __restrict__ WhhT,
    __bf16* __restrict__ aWihT, __bf16* __restrict__ aWhhT) {
    __shared__ float tile[64][65];
    int tb = blockIdx.x;
    const float* W; __bf16* WT; int NN;
    if (tb < 192)      { W = Wih;  WT = WihT;  NN = N3H; }
    else if (tb < 384) { W = Whh;  WT = WhhT;  NN = N3H; tb -= 192; }
    else if (tb < 448) { W = aWih; WT = aWihT; NN = HH;  tb -= 384; }
    else               { W = aWhh; WT = aWhhT; NN = HH;  tb -= 448; }
    const int ntn = NN >> 6;
    const int kb = (tb / ntn) * 64, nb = (tb % ntn) * 64;
    const int t = threadIdx.x;
#pragma unroll
    for (int it = 0; it < 16; ++it) {
        const int idx = it * 256 + t;
        const int kk = idx >> 6, nn = idx & 63;
        tile[kk][nn] = W[(size_t)(kb + kk) * NN + nb + nn];
    }
    __syncthreads();
#pragma unroll
    for (int it = 0; it < 16; ++it) {
        const int idx = it * 256 + t;
        const int nn = idx >> 6, kk = idx & 63;
        WT[(size_t)(nb + nn) * DD + kb + kk] = (__bf16)tile[kk][nn];
    }
}

// ---------------------------------------------------------------------------
// MFMA GEMM core: 128x128 block tile, BK=64, 256 threads (4 waves, 2x2),
// each wave 4x4 of 16x16x32 bf16 MFMA tiles. A (M x K row-major, at block
// row), B (N x K row-major = B^T, at block col row). XOR-swizzled LDS,
// global_load_lds width 16, conflict-free ds_read_b128.
// ---------------------------------------------------------------------------
__device__ __forceinline__ void mfma_pass(
    const __bf16* __restrict__ A, const __bf16* __restrict__ B, int K,
    __bf16* As, __bf16* Bs, f32x4 (&acc)[4][4], int tid) {
    const int lane = tid & 63;
    const int wave = tid >> 6;
    const int ln = lane & 15, q = lane >> 4;
    const int wm = (wave & 1) * 64, wn = (wave >> 1) * 64;
    const int sm  = tid >> 3;    // staging row (0..31), +32*r
    const int scs = tid & 7;     // staging chunk slot

    for (int k0 = 0; k0 < K; k0 += 64) {
        __syncthreads();
#pragma unroll
        for (int r = 0; r < 4; ++r) {
            const int m = sm + r * 32;
            const int c = scs ^ (m & 7);
            GL_LDS(A + (size_t)m * K + k0 + c * 8, As + m * 64 + scs * 8);
        }
#pragma unroll
        for (int r = 0; r < 4; ++r) {
            const int n = sm + r * 32;
            const int c = scs ^ (n & 7);
            GL_LDS(B + (size_t)n * K + k0 + c * 8, Bs + n * 64 + scs * 8);
        }
        __syncthreads();
#pragma unroll
        for (int kk = 0; kk < 64; kk += 32) {
            bf16x8 af[4], bfr[4];
#pragma unroll
            for (int ti = 0; ti < 4; ++ti) {
                const int m = wm + ti * 16 + ln;
                const int cs = ((kk >> 3) + q) ^ (m & 7);
                af[ti] = *(const bf16x8*)&As[m * 64 + cs * 8];
            }
#pragma unroll
            for (int tj = 0; tj < 4; ++tj) {
                const int n = wn + tj * 16 + ln;
                const int cs = ((kk >> 3) + q) ^ (n & 7);
                bfr[tj] = *(const bf16x8*)&Bs[n * 64 + cs * 8];
            }
#pragma unroll
            for (int ti = 0; ti < 4; ++ti)
#pragma unroll
                for (int tj = 0; tj < 4; ++tj)
                    acc[ti][tj] = __builtin_amdgcn_mfma_f32_16x16x32_bf16(
                        af[ti], bfr[tj], acc[ti][tj], 0, 0, 0);
        }
    }
}

// ---------------------------------------------------------------------------
// K1: gates4 (4096 x 2048) fp32.
//   cols [0,1536):  sig/sig/tanh( in@Wih + h0@Whh + bias )
//   cols [1536,2048): in@aWih + abias (raw)
// ---------------------------------------------------------------------------
__global__ __launch_bounds__(256, 2) void k_gates_mfma(
    const __bf16* __restrict__ in_bf, const __bf16* __restrict__ h0_bf,
    const __bf16* __restrict__ WihT, const __bf16* __restrict__ WhhT,
    const __bf16* __restrict__ aWihT, const float* __restrict__ bias,
    const float* __restrict__ abias, float* __restrict__ gates4) {
    __shared__ __bf16 As[128 * 64];
    __shared__ __bf16 Bs[128 * 64];
    f32x4 acc[4][4];
#pragma unroll
    for (int i = 0; i < 4; ++i)
#pragma unroll
        for (int j = 0; j < 4; ++j) acc[i][j] = (f32x4)0.f;

    const int n0 = blockIdx.x * 128;
    const int m0 = blockIdx.y * 128;
    const int tid = threadIdx.x;

    if (n0 < N3H) {
        mfma_pass(in_bf + (size_t)m0 * DD, WihT + (size_t)n0 * DD, DD, As, Bs, acc, tid);
        mfma_pass(h0_bf + (size_t)m0 * HH, WhhT + (size_t)n0 * DD, HH, As, Bs, acc, tid);
    } else {
        mfma_pass(in_bf + (size_t)m0 * DD, aWihT + (size_t)(n0 - N3H) * DD, DD, As, Bs, acc, tid);
    }

    const int lane = tid & 63, wave = tid >> 6;
    const int ln = lane & 15, q = lane >> 4;
    const int wm = (wave & 1) * 64, wn = (wave >> 1) * 64;
    const int region = n0 >> 9;  // 0,1: sigmoid; 2: tanh; 3: none

#pragma unroll
    for (int ti = 0; ti < 4; ++ti) {
#pragma unroll
        for (int tj = 0; tj < 4; ++tj) {
            const int col = n0 + wn + tj * 16 + ln;
            const float bv = (region < 3) ? bias[col] : abias[col - N3H];
#pragma unroll
            for (int reg = 0; reg < 4; ++reg) {
                const int row = m0 + wm + ti * 16 + q * 4 + reg;
                float x = acc[ti][tj][reg] + bv;
                if (region <= 1)      x = 1.f / (1.f + __expf(-x));
                else if (region == 2) x = tanhf(x);
                gates4[(size_t)row * N4H + col] = x;
            }
        }
    }
}

// ---------------------------------------------------------------------------
// K2: alpha GEMM (32768 x 512) with fully fused final epilogue.
// Each 16-row MFMA tile holds exactly 2 b-groups (C=8 rows each); reduce the
// c-axis in-register (4 regs) + one shfl_xor(16), then write h1/c1 directly.
// ---------------------------------------------------------------------------
__global__ __launch_bounds__(256, 2) void k_alpha_final(
    const __bf16* __restrict__ c_bf, const __bf16* __restrict__ aWhhT,
    const float* __restrict__ c_f32, const float* __restrict__ gates4,
    const float* __restrict__ maskmul, float* __restrict__ out) {
    __shared__ __bf16 As[128 * 64];
    __shared__ __bf16 Bs[128 * 64];
    __shared__ float maskLDS[128];
    f32x4 acc[4][4];
#pragma unroll
    for (int i = 0; i < 4; ++i)
#pragma unroll
        for (int j = 0; j < 4; ++j) acc[i][j] = (f32x4)0.f;

    const int n0 = blockIdx.x * 128;
    const int m0 = blockIdx.y * 128;
    const int tid = threadIdx.x;
    if (tid < 128) maskLDS[tid] = maskmul[m0 + tid];

    mfma_pass(c_bf + (size_t)m0 * HH, aWhhT + (size_t)n0 * DD, HH, As, Bs, acc, tid);

    const int lane = tid & 63, wave = tid >> 6;
    const int ln = lane & 15, q = lane >> 4;
    const int wm = (wave & 1) * 64, wn = (wave >> 1) * 64;

#pragma unroll
    for (int ti = 0; ti < 4; ++ti) {
        const int rbase = wm + ti * 16 + q * 4;        // local row of quad
        const int bg = (m0 + rbase) >> 3;              // global b for this quad
        float mm[4];
#pragma unroll
        for (int reg = 0; reg < 4; ++reg) mm[reg] = maskLDS[rbase + reg];
#pragma unroll
        for (int tj = 0; tj < 4; ++tj) {
            const int h = n0 + wn + tj * 16 + ln;
            const float awi = gates4[(size_t)bg * N4H + N3H + h];
            float sden = 0.f, snum = 0.f;
#pragma unroll
            for (int reg = 0; reg < 4; ++reg) {
                const int rg = m0 + rbase + reg;
                const float s = 1.f / (1.f + __expf(-(acc[ti][tj][reg] + awi)));
                const float a = __expf(s * mm[reg]);   // masked -> exp(-huge) = 0
                const float cin = c_f32[(size_t)rg * HH + h];
                sden += a;
                snum = fmaf(cin, a, snum);
            }
            sden += __shfl_xor(sden, 16);
            snum += __shfl_xor(snum, 16);
            if ((q & 1) == 0) {
                const float i_s = gates4[(size_t)bg * N4H + h];
                const float o_s = gates4[(size_t)bg * N4H + 512 + h];
                const float g_t = gates4[(size_t)bg * N4H + 1024 + h];
                const float e = __expf(i_s);
                const float c1 = fmaf(g_t, e, snum) / (e + sden);
                out[(size_t)bg * HH + h] = o_s * tanhf(c1);
                out[(size_t)BB * HH + (size_t)bg * HH + h] = c1;
            }
        }
    }
}

// ---------------------------------------------------------------------------
extern "C" void kernel_launch(void* const* d_in, const int* in_sizes, int n_in,
                              void* d_out, int out_size, void* d_ws, size_t ws_size,
                              hipStream_t stream) {
    const float* input = (const float*)d_in[0];
    const float* h0    = (const float*)d_in[1];
    // d_in[2] = c_0 (unused by reference)
    const float* c_in  = (const float*)d_in[3];
    const float* Wih   = (const float*)d_in[4];
    const float* Whh   = (const float*)d_in[5];
    const float* bias  = (const float*)d_in[6];
    const float* aWih  = (const float*)d_in[7];
    const float* aWhh  = (const float*)d_in[8];
    const float* abias = (const float*)d_in[9];
    float* out = (float*)d_out;

    // workspace layout (bytes)
    uint8_t* w = (uint8_t*)d_ws;
    __bf16* c_bf  = (__bf16*)w;                          // 32 MB
    __bf16* in_bf = (__bf16*)(w + (32u << 20));          //  4 MB
    __bf16* h0_bf = (__bf16*)(w + (36u << 20));          //  4 MB
    __bf16* WihT  = (__bf16*)(w + (40u << 20));          //  1.5 MB
    __bf16* WhhT  = (__bf16*)(w + (42u << 20));          //  1.5 MB
    __bf16* aWihT = (__bf16*)(w + (44u << 20));          //  0.5 MB
    __bf16* aWhhT = (__bf16*)(w + (45u << 20));          //  0.5 MB
    float* gates4  = (float*)(w + (46u << 20));          // 32 MB
    float* maskmul = (float*)(w + (78u << 20));          // 128 KB

    k_prep_c<<<dim3(BB * CC / 4), dim3(256), 0, stream>>>(c_in, c_bf, maskmul);
    k_prep_ih<<<dim3(2 * BB * DD / (256 * 8)), dim3(256), 0, stream>>>(input, h0, in_bf, h0_bf);
    k_prep_w<<<dim3(512), dim3(256), 0, stream>>>(Wih, Whh, aWih, aWhh,
                                                  WihT, WhhT, aWihT, aWhhT);
    k_gates_mfma<<<dim3(N4H / 128, BB / 128), dim3(256), 0, stream>>>(
        in_bf, h0_bf, WihT, WhhT, aWihT, bias, abias, gates4);
    k_alpha_final<<<dim3(HH / 128, BB * CC / 128), dim3(256), 0, stream>>>(
        c_bf, aWhhT, c_in, gates4, maskmul, out);
}